// Round 1
// baseline (4743.705 us; speedup 1.0000x reference)
//
#include <hip/hip_runtime.h>

#define IN_DIM 500
#define HID 8
#define ODIM 3

// ---------------------------------------------------------------------------
// Kernel A: support1[row][0..7] = x[row][:] @ W1   (wave-per-row, K split
// across 64 lanes, W1 slice cached in per-lane registers, butterfly reduce)
// ---------------------------------------------------------------------------
__global__ __launch_bounds__(256) void k_support1(
    const float* __restrict__ x, const float* __restrict__ W1,
    float* __restrict__ s1, int nRows)
{
    const int lane = threadIdx.x & 63;
    const int wid  = blockIdx.x * (blockDim.x >> 6) + (threadIdx.x >> 6);
    const int nw   = gridDim.x * (blockDim.x >> 6);

    // per-lane W1 cache: this lane consumes k = 4*lane + 256*i + c (fixed for
    // all rows). 2*4*8 = 64 VGPRs. Out-of-range k -> 0 so tail needs no branch.
    float w[2][4][8];
#pragma unroll
    for (int i = 0; i < 2; ++i)
#pragma unroll
        for (int c = 0; c < 4; ++c) {
            const int k = 4 * lane + 256 * i + c;
#pragma unroll
            for (int j = 0; j < HID; ++j)
                w[i][c][j] = (k < IN_DIM) ? W1[k * HID + j] : 0.0f;
        }

    for (int row = wid; row < nRows; row += nw) {
        const float* xr = x + (size_t)row * IN_DIM;
        float acc[8] = {0.f, 0.f, 0.f, 0.f, 0.f, 0.f, 0.f, 0.f};
#pragma unroll
        for (int i = 0; i < 2; ++i) {
            const int k = 4 * lane + 256 * i;
            float4 v = make_float4(0.f, 0.f, 0.f, 0.f);
            // IN_DIM = 500 = 4*125, rows are 2000B apart -> every float4 slot
            // is either fully in-range or fully out; base stays 16B-aligned.
            if (k + 3 < IN_DIM) v = *(const float4*)(xr + k);
#pragma unroll
            for (int j = 0; j < HID; ++j)
                acc[j] += v.x * w[i][0][j] + v.y * w[i][1][j]
                        + v.z * w[i][2][j] + v.w * w[i][3][j];
        }
        // full 64-lane butterfly; all indices compile-time (no scratch)
#pragma unroll
        for (int m = 32; m >= 1; m >>= 1)
#pragma unroll
            for (int j = 0; j < HID; ++j)
                acc[j] += __shfl_xor(acc[j], m, 64);
        if (lane == 0) {
            float4* o = (float4*)(s1 + (size_t)row * HID);
            o[0] = make_float4(acc[0], acc[1], acc[2], acc[3]);
            o[1] = make_float4(acc[4], acc[5], acc[6], acc[7]);
        }
    }
}

// ---------------------------------------------------------------------------
// Kernel B: agg[dst] += support1[src]  (8 f32 HW atomics per edge)
// ---------------------------------------------------------------------------
__global__ __launch_bounds__(256) void k_scatter1(
    const int* __restrict__ ei, int nE,
    const float* __restrict__ s1, float* __restrict__ agg)
{
    int e = blockIdx.x * blockDim.x + threadIdx.x;
    const int stride = gridDim.x * blockDim.x;
    for (; e < nE; e += stride) {
        const int src = ei[e];
        const int dst = ei[nE + e];
        const float4* sp = (const float4*)(s1 + (size_t)src * HID);
        const float4 a = sp[0];
        const float4 b = sp[1];
        float* ap = agg + (size_t)dst * HID;
        unsafeAtomicAdd(ap + 0, a.x); unsafeAtomicAdd(ap + 1, a.y);
        unsafeAtomicAdd(ap + 2, a.z); unsafeAtomicAdd(ap + 3, a.w);
        unsafeAtomicAdd(ap + 4, b.x); unsafeAtomicAdd(ap + 5, b.y);
        unsafeAtomicAdd(ap + 6, b.z); unsafeAtomicAdd(ap + 7, b.w);
    }
}

// ---------------------------------------------------------------------------
// Kernel C: h = relu(agg + b1); s2 = h @ W2 ; also out[i][:] = b2 (init for
// the second scatter)
// ---------------------------------------------------------------------------
__global__ __launch_bounds__(256) void k_hidden(
    const float* __restrict__ agg, const float* __restrict__ b1,
    const float* __restrict__ W2, const float* __restrict__ b2,
    float* __restrict__ s2, float* __restrict__ out, int n)
{
    int i = blockIdx.x * blockDim.x + threadIdx.x;
    const int stride = gridDim.x * blockDim.x;

    float w2[HID][ODIM];
#pragma unroll
    for (int k = 0; k < HID; ++k)
#pragma unroll
        for (int j = 0; j < ODIM; ++j)
            w2[k][j] = W2[k * ODIM + j];
    float bb1[HID];
#pragma unroll
    for (int k = 0; k < HID; ++k) bb1[k] = b1[k];
    const float bb2_0 = b2[0], bb2_1 = b2[1], bb2_2 = b2[2];

    for (; i < n; i += stride) {
        const float4* ap = (const float4*)(agg + (size_t)i * HID);
        const float4 a = ap[0];
        const float4 b = ap[1];
        float h[HID];
        h[0] = fmaxf(a.x + bb1[0], 0.f); h[1] = fmaxf(a.y + bb1[1], 0.f);
        h[2] = fmaxf(a.z + bb1[2], 0.f); h[3] = fmaxf(a.w + bb1[3], 0.f);
        h[4] = fmaxf(b.x + bb1[4], 0.f); h[5] = fmaxf(b.y + bb1[5], 0.f);
        h[6] = fmaxf(b.z + bb1[6], 0.f); h[7] = fmaxf(b.w + bb1[7], 0.f);
        float o0 = 0.f, o1 = 0.f, o2 = 0.f;
#pragma unroll
        for (int k = 0; k < HID; ++k) {
            o0 += h[k] * w2[k][0];
            o1 += h[k] * w2[k][1];
            o2 += h[k] * w2[k][2];
        }
        s2[(size_t)i * ODIM + 0] = o0;
        s2[(size_t)i * ODIM + 1] = o1;
        s2[(size_t)i * ODIM + 2] = o2;
        out[(size_t)i * ODIM + 0] = bb2_0;
        out[(size_t)i * ODIM + 1] = bb2_1;
        out[(size_t)i * ODIM + 2] = bb2_2;
    }
}

// ---------------------------------------------------------------------------
// Kernel D: out[dst] += s2[src]  (3 f32 HW atomics per edge)
// ---------------------------------------------------------------------------
__global__ __launch_bounds__(256) void k_scatter2(
    const int* __restrict__ ei, int nE,
    const float* __restrict__ s2, float* __restrict__ out)
{
    int e = blockIdx.x * blockDim.x + threadIdx.x;
    const int stride = gridDim.x * blockDim.x;
    for (; e < nE; e += stride) {
        const int src = ei[e];
        const int dst = ei[nE + e];
        const float v0 = s2[(size_t)src * ODIM + 0];
        const float v1 = s2[(size_t)src * ODIM + 1];
        const float v2 = s2[(size_t)src * ODIM + 2];
        float* op = out + (size_t)dst * ODIM;
        unsafeAtomicAdd(op + 0, v0);
        unsafeAtomicAdd(op + 1, v1);
        unsafeAtomicAdd(op + 2, v2);
    }
}

// ---------------------------------------------------------------------------
extern "C" void kernel_launch(void* const* d_in, const int* in_sizes, int n_in,
                              void* d_out, int out_size, void* d_ws, size_t ws_size,
                              hipStream_t stream)
{
    const float* x  = (const float*)d_in[0];
    const int*   ei = (const int*)d_in[1];   // [2, E] int32, row0=src row1=dst
    const float* W1 = (const float*)d_in[2];
    const float* b1 = (const float*)d_in[3];
    const float* W2 = (const float*)d_in[4];
    const float* b2 = (const float*)d_in[5];
    float* out = (float*)d_out;

    const int nE = in_sizes[1] / 2;
    const int nN = in_sizes[0] / IN_DIM;

    float* s1  = (float*)d_ws;                 // nN*8 f32 = 8 MB
    float* agg = s1 + (size_t)nN * HID;        // nN*8 f32 = 8 MB
    float* s2  = agg + (size_t)nN * HID;       // nN*3 f32 = 3 MB

    hipMemsetAsync(agg, 0, (size_t)nN * HID * sizeof(float), stream);
    k_support1<<<2048, 256, 0, stream>>>(x, W1, s1, nN);
    k_scatter1<<<4096, 256, 0, stream>>>(ei, nE, s1, agg);
    k_hidden  <<<1024, 256, 0, stream>>>(agg, b1, W2, b2, s2, out, nN);
    k_scatter2<<<4096, 256, 0, stream>>>(ei, nE, s2, out);
}

// Round 2
// 849.615 us; speedup vs baseline: 5.5834x; 5.5834x over previous
//
#include <hip/hip_runtime.h>

#define IN_DIM 500
#define HID 8
#define ODIM 3
#define NB 1024          // buckets = nN >> 8 (nN = 262144 fixed)
#define BSHIFT 8         // 256 nodes per bucket

// ---------------------------------------------------------------------------
// Kernel A: support1[row][0..7] = x[row][:] @ W1   (wave-per-row, K split
// across 64 lanes, W1 slice cached in per-lane registers, butterfly reduce)
// ---------------------------------------------------------------------------
__global__ __launch_bounds__(256) void k_support1(
    const float* __restrict__ x, const float* __restrict__ W1,
    float* __restrict__ s1, int nRows)
{
    const int lane = threadIdx.x & 63;
    const int wid  = blockIdx.x * (blockDim.x >> 6) + (threadIdx.x >> 6);
    const int nw   = gridDim.x * (blockDim.x >> 6);

    float w[2][4][8];
#pragma unroll
    for (int i = 0; i < 2; ++i)
#pragma unroll
        for (int c = 0; c < 4; ++c) {
            const int k = 4 * lane + 256 * i + c;
#pragma unroll
            for (int j = 0; j < HID; ++j)
                w[i][c][j] = (k < IN_DIM) ? W1[k * HID + j] : 0.0f;
        }

    for (int row = wid; row < nRows; row += nw) {
        const float* xr = x + (size_t)row * IN_DIM;
        float acc[8] = {0.f, 0.f, 0.f, 0.f, 0.f, 0.f, 0.f, 0.f};
#pragma unroll
        for (int i = 0; i < 2; ++i) {
            const int k = 4 * lane + 256 * i;
            float4 v = make_float4(0.f, 0.f, 0.f, 0.f);
            if (k + 3 < IN_DIM) v = *(const float4*)(xr + k);
#pragma unroll
            for (int j = 0; j < HID; ++j)
                acc[j] += v.x * w[i][0][j] + v.y * w[i][1][j]
                        + v.z * w[i][2][j] + v.w * w[i][3][j];
        }
#pragma unroll
        for (int m = 32; m >= 1; m >>= 1)
#pragma unroll
            for (int j = 0; j < HID; ++j)
                acc[j] += __shfl_xor(acc[j], m, 64);
        if (lane == 0) {
            float4* o = (float4*)(s1 + (size_t)row * HID);
            o[0] = make_float4(acc[0], acc[1], acc[2], acc[3]);
            o[1] = make_float4(acc[4], acc[5], acc[6], acc[7]);
        }
    }
}

// ---------------------------------------------------------------------------
// Kernel B1: per-bucket edge histogram (LDS-aggregated -> global totals)
// ---------------------------------------------------------------------------
__global__ __launch_bounds__(256) void k_count(
    const int* __restrict__ dst, int nE, int chunk,
    unsigned* __restrict__ totals)
{
    __shared__ unsigned lh[NB];
    for (int b = threadIdx.x; b < NB; b += 256) lh[b] = 0;
    __syncthreads();
    const int beg = blockIdx.x * chunk;
    const int end = min(nE, beg + chunk);
    for (int e = beg + threadIdx.x; e < end; e += 256)
        atomicAdd(&lh[((unsigned)dst[e]) >> BSHIFT], 1u);
    __syncthreads();
    for (int b = threadIdx.x; b < NB; b += 256) {
        const unsigned c = lh[b];
        if (c) atomicAdd(&totals[b], c);
    }
}

// ---------------------------------------------------------------------------
// Kernel B2: exclusive scan of 1024 bucket totals (single block)
// ---------------------------------------------------------------------------
__global__ __launch_bounds__(256) void k_scan(
    const unsigned* __restrict__ totals,
    unsigned* __restrict__ starts, unsigned* __restrict__ cursor)
{
    __shared__ unsigned sums[256];
    const int t = threadIdx.x;
    unsigned v[4];
    unsigned s = 0;
#pragma unroll
    for (int c = 0; c < 4; ++c) { v[c] = totals[t * 4 + c]; s += v[c]; }
    sums[t] = s;
    __syncthreads();
    for (int off = 1; off < 256; off <<= 1) {
        const unsigned u = (t >= off) ? sums[t - off] : 0u;
        __syncthreads();
        sums[t] += u;
        __syncthreads();
    }
    unsigned base = sums[t] - s;   // exclusive prefix of this thread's group
#pragma unroll
    for (int c = 0; c < 4; ++c) {
        starts[t * 4 + c] = base;
        cursor[t * 4 + c] = base;
        base += v[c];
    }
    if (t == 255) starts[NB] = base;
}

// ---------------------------------------------------------------------------
// Kernel B3: counting-sort edges into buckets; pack (src<<8)|local_dst
// ---------------------------------------------------------------------------
__global__ __launch_bounds__(256) void k_binwrite(
    const int* __restrict__ ei, int nE, int chunk,
    unsigned* __restrict__ cursor, unsigned* __restrict__ binned)
{
    __shared__ unsigned lh[NB];
    __shared__ unsigned lbase[NB];
    for (int b = threadIdx.x; b < NB; b += 256) lh[b] = 0;
    __syncthreads();
    const int beg = blockIdx.x * chunk;
    const int end = min(nE, beg + chunk);
    for (int e = beg + threadIdx.x; e < end; e += 256)
        atomicAdd(&lh[((unsigned)ei[nE + e]) >> BSHIFT], 1u);
    __syncthreads();
    for (int b = threadIdx.x; b < NB; b += 256) {
        const unsigned c = lh[b];
        lbase[b] = c ? atomicAdd(&cursor[b], c) : 0u;
        lh[b] = 0;
    }
    __syncthreads();
    for (int e = beg + threadIdx.x; e < end; e += 256) {
        const unsigned d = (unsigned)ei[nE + e];
        const unsigned s = (unsigned)ei[e];
        const unsigned b = d >> BSHIFT;
        const unsigned r = atomicAdd(&lh[b], 1u);
        binned[lbase[b] + r] = (s << 8) | (d & 255u);
    }
}

// ---------------------------------------------------------------------------
// Kernel C: per-bucket gather of layer-1 + fused relu(+b1) @ W2 -> s2 (pad 4)
// ---------------------------------------------------------------------------
__global__ __launch_bounds__(256) void k_gather1(
    const unsigned* __restrict__ binned, const unsigned* __restrict__ starts,
    const float* __restrict__ s1, const float* __restrict__ b1,
    const float* __restrict__ W2, float* __restrict__ s2)
{
    __shared__ float acc[256][HID];
    const int t = threadIdx.x;
#pragma unroll
    for (int j = 0; j < HID; ++j) acc[t][j] = 0.f;
    __syncthreads();
    const unsigned beg = starts[blockIdx.x];
    const unsigned end = starts[blockIdx.x + 1];
    for (unsigned i = beg + t; i < end; i += 256) {
        const unsigned p = binned[i];
        const unsigned src = p >> 8, l = p & 255u;
        const float4* sp = (const float4*)(s1 + (size_t)src * HID);
        const float4 a = sp[0];
        const float4 b = sp[1];
        atomicAdd(&acc[l][0], a.x); atomicAdd(&acc[l][1], a.y);
        atomicAdd(&acc[l][2], a.z); atomicAdd(&acc[l][3], a.w);
        atomicAdd(&acc[l][4], b.x); atomicAdd(&acc[l][5], b.y);
        atomicAdd(&acc[l][6], b.z); atomicAdd(&acc[l][7], b.w);
    }
    __syncthreads();
    float h[HID];
#pragma unroll
    for (int j = 0; j < HID; ++j) h[j] = fmaxf(acc[t][j] + b1[j], 0.f);
    float o0 = 0.f, o1 = 0.f, o2 = 0.f;
#pragma unroll
    for (int k = 0; k < HID; ++k) {
        o0 += h[k] * W2[k * ODIM + 0];
        o1 += h[k] * W2[k * ODIM + 1];
        o2 += h[k] * W2[k * ODIM + 2];
    }
    const size_t node = ((size_t)blockIdx.x << BSHIFT) + t;
    *(float4*)(s2 + node * 4) = make_float4(o0, o1, o2, 0.f);
}

// ---------------------------------------------------------------------------
// Kernel D: per-bucket gather of layer-2 -> out = acc + b2  (no atomics)
// ---------------------------------------------------------------------------
__global__ __launch_bounds__(256) void k_gather2(
    const unsigned* __restrict__ binned, const unsigned* __restrict__ starts,
    const float* __restrict__ s2, const float* __restrict__ b2,
    float* __restrict__ out)
{
    __shared__ float acc[256][4];
    const int t = threadIdx.x;
#pragma unroll
    for (int j = 0; j < 4; ++j) acc[t][j] = 0.f;
    __syncthreads();
    const unsigned beg = starts[blockIdx.x];
    const unsigned end = starts[blockIdx.x + 1];
    for (unsigned i = beg + t; i < end; i += 256) {
        const unsigned p = binned[i];
        const unsigned src = p >> 8, l = p & 255u;
        const float4 v = *(const float4*)(s2 + (size_t)src * 4);
        atomicAdd(&acc[l][0], v.x);
        atomicAdd(&acc[l][1], v.y);
        atomicAdd(&acc[l][2], v.z);
    }
    __syncthreads();
    // coalesced write of 256 nodes x 3 floats
    const size_t base = ((size_t)blockIdx.x << BSHIFT) * ODIM;
    for (int i = t; i < 256 * ODIM; i += 256) {
        const int n = i / ODIM, j = i - n * ODIM;
        out[base + i] = acc[n][j] + b2[j];
    }
}

// ---------------------------------------------------------------------------
extern "C" void kernel_launch(void* const* d_in, const int* in_sizes, int n_in,
                              void* d_out, int out_size, void* d_ws, size_t ws_size,
                              hipStream_t stream)
{
    const float* x  = (const float*)d_in[0];
    const int*   ei = (const int*)d_in[1];   // [2, E] int32, row0=src row1=dst
    const float* W1 = (const float*)d_in[2];
    const float* b1 = (const float*)d_in[3];
    const float* W2 = (const float*)d_in[4];
    const float* b2 = (const float*)d_in[5];
    float* out = (float*)d_out;

    const int nE = in_sizes[1] / 2;           // 8388608
    const int nN = in_sizes[0] / IN_DIM;      // 262144

    // workspace layout (~46 MB)
    unsigned* binned = (unsigned*)d_ws;                       // nE u32 = 33.5 MB
    float*    s1     = (float*)(binned + nE);                 // nN*8 f32 = 8 MB
    float*    s2     = s1 + (size_t)nN * HID;                 // nN*4 f32 = 4 MB
    unsigned* totals = (unsigned*)(s2 + (size_t)nN * 4);      // NB
    unsigned* starts = totals + NB;                           // NB+1
    unsigned* cursor = starts + NB + 1;                       // NB

    hipMemsetAsync(totals, 0, NB * sizeof(unsigned), stream);

    const int P = 512;
    const int chunk = (nE + P - 1) / P;

    k_support1<<<2048, 256, 0, stream>>>(x, W1, s1, nN);
    k_count   <<<P,    256, 0, stream>>>(ei + nE, nE, chunk, totals);
    k_scan    <<<1,    256, 0, stream>>>(totals, starts, cursor);
    k_binwrite<<<P,    256, 0, stream>>>(ei, nE, chunk, cursor, binned);
    k_gather1 <<<NB,   256, 0, stream>>>(binned, starts, s1, b1, W2, s2);
    k_gather2 <<<NB,   256, 0, stream>>>(binned, starts, s2, b2, out);
}

// Round 3
// 819.047 us; speedup vs baseline: 5.7917x; 1.0373x over previous
//
#include <hip/hip_runtime.h>

#define IN_DIM 500
#define HID 8
#define ODIM 3
#define NB 1024          // buckets (nN = 262144 -> 256 nodes/bucket)
#define BSHIFT 8
#define PBLK 256         // blocks for count/binwrite passes

// ---------------------------------------------------------------------------
// Kernel A: support1[row][0..7] = x[row][:] @ W1   (wave-per-row, K split
// across 64 lanes, W1 slice cached in per-lane registers, butterfly reduce)
// ---------------------------------------------------------------------------
__global__ __launch_bounds__(256) void k_support1(
    const float* __restrict__ x, const float* __restrict__ W1,
    float* __restrict__ s1, int nRows)
{
    const int lane = threadIdx.x & 63;
    const int wid  = blockIdx.x * (blockDim.x >> 6) + (threadIdx.x >> 6);
    const int nw   = gridDim.x * (blockDim.x >> 6);

    float w[2][4][8];
#pragma unroll
    for (int i = 0; i < 2; ++i)
#pragma unroll
        for (int c = 0; c < 4; ++c) {
            const int k = 4 * lane + 256 * i + c;
#pragma unroll
            for (int j = 0; j < HID; ++j)
                w[i][c][j] = (k < IN_DIM) ? W1[k * HID + j] : 0.0f;
        }

    for (int row = wid; row < nRows; row += nw) {
        const float* xr = x + (size_t)row * IN_DIM;
        float acc[8] = {0.f, 0.f, 0.f, 0.f, 0.f, 0.f, 0.f, 0.f};
#pragma unroll
        for (int i = 0; i < 2; ++i) {
            const int k = 4 * lane + 256 * i;
            float4 v = make_float4(0.f, 0.f, 0.f, 0.f);
            if (k + 3 < IN_DIM) v = *(const float4*)(xr + k);
#pragma unroll
            for (int j = 0; j < HID; ++j)
                acc[j] += v.x * w[i][0][j] + v.y * w[i][1][j]
                        + v.z * w[i][2][j] + v.w * w[i][3][j];
        }
#pragma unroll
        for (int m = 32; m >= 1; m >>= 1)
#pragma unroll
            for (int j = 0; j < HID; ++j)
                acc[j] += __shfl_xor(acc[j], m, 64);
        if (lane == 0) {
            float4* o = (float4*)(s1 + (size_t)row * HID);
            o[0] = make_float4(acc[0], acc[1], acc[2], acc[3]);
            o[1] = make_float4(acc[4], acc[5], acc[6], acc[7]);
        }
    }
}

// ---------------------------------------------------------------------------
// Kernel B1: per-block bucket histogram -> counts[block][b]  (no global atomics)
// ---------------------------------------------------------------------------
__global__ __launch_bounds__(1024) void k_count(
    const int* __restrict__ dst, int nE, int chunk,
    unsigned* __restrict__ counts)
{
    __shared__ unsigned lh[NB];
    for (int i = threadIdx.x; i < NB; i += 1024) lh[i] = 0;
    __syncthreads();
    const int beg = blockIdx.x * chunk;
    const int end = min(nE, beg + chunk);
    for (int e = beg + threadIdx.x; e < end; e += 1024)
        atomicAdd(&lh[((unsigned)dst[e]) >> BSHIFT], 1u);
    __syncthreads();
    for (int i = threadIdx.x; i < NB; i += 1024)
        counts[(size_t)blockIdx.x * NB + i] = lh[i];
}

// ---------------------------------------------------------------------------
// Kernel B2: column-wise exclusive prefix over counts (in place) + bucket
// starts via LDS scan. One block, 1024 threads (thread = bucket).
// ---------------------------------------------------------------------------
__global__ __launch_bounds__(1024) void k_scanM(
    unsigned* __restrict__ counts, unsigned* __restrict__ starts)
{
    __shared__ unsigned sums[NB];
    const int b = threadIdx.x;
    unsigned run = 0;
    for (int p = 0; p < PBLK; ++p) {
        const unsigned c = counts[(size_t)p * NB + b];
        counts[(size_t)p * NB + b] = run;   // per-block offset within bucket
        run += c;
    }
    const unsigned total = run;
    sums[b] = run;
    __syncthreads();
    for (int off = 1; off < NB; off <<= 1) {
        const unsigned u = (b >= off) ? sums[b - off] : 0u;
        __syncthreads();
        sums[b] += u;
        __syncthreads();
    }
    starts[b] = sums[b] - total;       // exclusive
    if (b == NB - 1) starts[NB] = sums[b];
}

// ---------------------------------------------------------------------------
// Kernel B3: counting-sort edges into buckets; pack (src<<8)|local_dst.
// Zero global atomics: base = starts[b] + counts[block][b].
// ---------------------------------------------------------------------------
__global__ __launch_bounds__(1024) void k_binwrite(
    const int* __restrict__ ei, int nE, int chunk,
    const unsigned* __restrict__ counts, const unsigned* __restrict__ starts,
    unsigned* __restrict__ binned)
{
    __shared__ unsigned lh[NB];
    __shared__ unsigned lbase[NB];
    for (int i = threadIdx.x; i < NB; i += 1024) {
        lh[i] = 0;
        lbase[i] = starts[i] + counts[(size_t)blockIdx.x * NB + i];
    }
    __syncthreads();
    const int beg = blockIdx.x * chunk;
    const int end = min(nE, beg + chunk);
    for (int e = beg + threadIdx.x; e < end; e += 1024) {
        const unsigned d = (unsigned)ei[nE + e];
        const unsigned s = (unsigned)ei[e];
        const unsigned b = d >> BSHIFT;
        const unsigned r = atomicAdd(&lh[b], 1u);
        binned[lbase[b] + r] = (s << 8) | (d & 255u);
    }
}

// ---------------------------------------------------------------------------
// Kernel C: per-bucket gather of layer-1 + fused relu(+b1) @ W2 -> s2 (pad 4)
// 1024 threads, 4-way unrolled gather for MLP (memory-level parallelism).
// ---------------------------------------------------------------------------
__global__ __launch_bounds__(1024) void k_gather1(
    const unsigned* __restrict__ binned, const unsigned* __restrict__ starts,
    const float* __restrict__ s1, const float* __restrict__ b1,
    const float* __restrict__ W2, float* __restrict__ s2)
{
    __shared__ float acc[256][HID];     // 8 KB
    const int t = threadIdx.x;
    ((float2*)acc)[t] = make_float2(0.f, 0.f);   // 2048 floats
    __syncthreads();
    const unsigned beg = starts[blockIdx.x];
    const unsigned end = starts[blockIdx.x + 1];

    unsigned i = beg + t;
    for (; i + 3072 < end; i += 4096) {
        const unsigned p0 = binned[i];
        const unsigned p1 = binned[i + 1024];
        const unsigned p2 = binned[i + 2048];
        const unsigned p3 = binned[i + 3072];
        const float4* r0 = (const float4*)(s1 + (size_t)(p0 >> 8) * HID);
        const float4* r1 = (const float4*)(s1 + (size_t)(p1 >> 8) * HID);
        const float4* r2 = (const float4*)(s1 + (size_t)(p2 >> 8) * HID);
        const float4* r3 = (const float4*)(s1 + (size_t)(p3 >> 8) * HID);
        const float4 a0 = r0[0], b0 = r0[1];
        const float4 a1 = r1[0], b1v = r1[1];
        const float4 a2 = r2[0], b2v = r2[1];
        const float4 a3 = r3[0], b3v = r3[1];
        const unsigned l0 = p0 & 255u, l1 = p1 & 255u,
                       l2 = p2 & 255u, l3 = p3 & 255u;
        atomicAdd(&acc[l0][0], a0.x); atomicAdd(&acc[l0][1], a0.y);
        atomicAdd(&acc[l0][2], a0.z); atomicAdd(&acc[l0][3], a0.w);
        atomicAdd(&acc[l0][4], b0.x); atomicAdd(&acc[l0][5], b0.y);
        atomicAdd(&acc[l0][6], b0.z); atomicAdd(&acc[l0][7], b0.w);
        atomicAdd(&acc[l1][0], a1.x); atomicAdd(&acc[l1][1], a1.y);
        atomicAdd(&acc[l1][2], a1.z); atomicAdd(&acc[l1][3], a1.w);
        atomicAdd(&acc[l1][4], b1v.x); atomicAdd(&acc[l1][5], b1v.y);
        atomicAdd(&acc[l1][6], b1v.z); atomicAdd(&acc[l1][7], b1v.w);
        atomicAdd(&acc[l2][0], a2.x); atomicAdd(&acc[l2][1], a2.y);
        atomicAdd(&acc[l2][2], a2.z); atomicAdd(&acc[l2][3], a2.w);
        atomicAdd(&acc[l2][4], b2v.x); atomicAdd(&acc[l2][5], b2v.y);
        atomicAdd(&acc[l2][6], b2v.z); atomicAdd(&acc[l2][7], b2v.w);
        atomicAdd(&acc[l3][0], a3.x); atomicAdd(&acc[l3][1], a3.y);
        atomicAdd(&acc[l3][2], a3.z); atomicAdd(&acc[l3][3], a3.w);
        atomicAdd(&acc[l3][4], b3v.x); atomicAdd(&acc[l3][5], b3v.y);
        atomicAdd(&acc[l3][6], b3v.z); atomicAdd(&acc[l3][7], b3v.w);
    }
    for (; i < end; i += 1024) {
        const unsigned p = binned[i];
        const unsigned src = p >> 8, l = p & 255u;
        const float4* sp = (const float4*)(s1 + (size_t)src * HID);
        const float4 a = sp[0], b = sp[1];
        atomicAdd(&acc[l][0], a.x); atomicAdd(&acc[l][1], a.y);
        atomicAdd(&acc[l][2], a.z); atomicAdd(&acc[l][3], a.w);
        atomicAdd(&acc[l][4], b.x); atomicAdd(&acc[l][5], b.y);
        atomicAdd(&acc[l][6], b.z); atomicAdd(&acc[l][7], b.w);
    }
    __syncthreads();
    if (t < 256) {
        float h[HID];
#pragma unroll
        for (int j = 0; j < HID; ++j) h[j] = fmaxf(acc[t][j] + b1[j], 0.f);
        float o0 = 0.f, o1 = 0.f, o2 = 0.f;
#pragma unroll
        for (int k = 0; k < HID; ++k) {
            o0 += h[k] * W2[k * ODIM + 0];
            o1 += h[k] * W2[k * ODIM + 1];
            o2 += h[k] * W2[k * ODIM + 2];
        }
        const size_t node = ((size_t)blockIdx.x << BSHIFT) + t;
        *(float4*)(s2 + node * 4) = make_float4(o0, o1, o2, 0.f);
    }
}

// ---------------------------------------------------------------------------
// Kernel D: per-bucket gather of layer-2 -> out = acc + b2
// ---------------------------------------------------------------------------
__global__ __launch_bounds__(1024) void k_gather2(
    const unsigned* __restrict__ binned, const unsigned* __restrict__ starts,
    const float* __restrict__ s2, const float* __restrict__ b2,
    float* __restrict__ out)
{
    __shared__ float acc[256][4];       // 4 KB
    const int t = threadIdx.x;
    ((float*)acc)[t] = 0.f;             // 1024 floats
    __syncthreads();
    const unsigned beg = starts[blockIdx.x];
    const unsigned end = starts[blockIdx.x + 1];

    unsigned i = beg + t;
    for (; i + 3072 < end; i += 4096) {
        const unsigned p0 = binned[i];
        const unsigned p1 = binned[i + 1024];
        const unsigned p2 = binned[i + 2048];
        const unsigned p3 = binned[i + 3072];
        const float4 v0 = *(const float4*)(s2 + (size_t)(p0 >> 8) * 4);
        const float4 v1 = *(const float4*)(s2 + (size_t)(p1 >> 8) * 4);
        const float4 v2 = *(const float4*)(s2 + (size_t)(p2 >> 8) * 4);
        const float4 v3 = *(const float4*)(s2 + (size_t)(p3 >> 8) * 4);
        const unsigned l0 = p0 & 255u, l1 = p1 & 255u,
                       l2 = p2 & 255u, l3 = p3 & 255u;
        atomicAdd(&acc[l0][0], v0.x); atomicAdd(&acc[l0][1], v0.y);
        atomicAdd(&acc[l0][2], v0.z);
        atomicAdd(&acc[l1][0], v1.x); atomicAdd(&acc[l1][1], v1.y);
        atomicAdd(&acc[l1][2], v1.z);
        atomicAdd(&acc[l2][0], v2.x); atomicAdd(&acc[l2][1], v2.y);
        atomicAdd(&acc[l2][2], v2.z);
        atomicAdd(&acc[l3][0], v3.x); atomicAdd(&acc[l3][1], v3.y);
        atomicAdd(&acc[l3][2], v3.z);
    }
    for (; i < end; i += 1024) {
        const unsigned p = binned[i];
        const float4 v = *(const float4*)(s2 + (size_t)(p >> 8) * 4);
        const unsigned l = p & 255u;
        atomicAdd(&acc[l][0], v.x);
        atomicAdd(&acc[l][1], v.y);
        atomicAdd(&acc[l][2], v.z);
    }
    __syncthreads();
    if (t < 256 * ODIM) {
        const int n = t / ODIM, j = t - n * ODIM;
        const size_t base = ((size_t)blockIdx.x << BSHIFT) * ODIM;
        out[base + t] = acc[n][j] + b2[j];
    }
}

// ---------------------------------------------------------------------------
extern "C" void kernel_launch(void* const* d_in, const int* in_sizes, int n_in,
                              void* d_out, int out_size, void* d_ws, size_t ws_size,
                              hipStream_t stream)
{
    const float* x  = (const float*)d_in[0];
    const int*   ei = (const int*)d_in[1];   // [2, E] int32, row0=src row1=dst
    const float* W1 = (const float*)d_in[2];
    const float* b1 = (const float*)d_in[3];
    const float* W2 = (const float*)d_in[4];
    const float* b2 = (const float*)d_in[5];
    float* out = (float*)d_out;

    const int nE = in_sizes[1] / 2;           // 8388608
    const int nN = in_sizes[0] / IN_DIM;      // 262144

    // workspace layout (~46.6 MB)
    unsigned* binned = (unsigned*)d_ws;                       // nE u32 = 33.5 MB
    float*    s1     = (float*)(binned + nE);                 // nN*8 f32 = 8 MB
    float*    s2     = s1 + (size_t)nN * HID;                 // nN*4 f32 = 4 MB
    unsigned* counts = (unsigned*)(s2 + (size_t)nN * 4);      // PBLK*NB u32 = 1 MB
    unsigned* starts = counts + (size_t)PBLK * NB;            // NB+1

    const int chunk = (nE + PBLK - 1) / PBLK;

    k_support1<<<4096, 256,  0, stream>>>(x, W1, s1, nN);
    k_count   <<<PBLK, 1024, 0, stream>>>(ei + nE, nE, chunk, counts);
    k_scanM   <<<1,    1024, 0, stream>>>(counts, starts);
    k_binwrite<<<PBLK, 1024, 0, stream>>>(ei, nE, chunk, counts, starts, binned);
    k_gather1 <<<NB,   1024, 0, stream>>>(binned, starts, s1, b1, W2, s2);
    k_gather2 <<<NB,   1024, 0, stream>>>(binned, starts, s2, b2, out);
}

// Round 4
// 817.493 us; speedup vs baseline: 5.8027x; 1.0019x over previous
//
#include <hip/hip_runtime.h>

#define IN_DIM 500
#define HID 8
#define ODIM 3
#define NB 1024          // buckets (nN = 262144 -> 256 nodes/bucket)
#define BSHIFT 8
#define PBLK 256         // blocks for count/binwrite passes
#define S1W 9            // padded LDS stride for gather1 acc (odd -> all 32 banks)
#define S2W 5            // padded LDS stride for gather2 acc

// ---------------------------------------------------------------------------
// Kernel A: support1[row][0..7] = x[row][:] @ W1   (wave-per-row, K split
// across 64 lanes, W1 slice cached in per-lane registers, butterfly reduce)
// ---------------------------------------------------------------------------
__global__ __launch_bounds__(256) void k_support1(
    const float* __restrict__ x, const float* __restrict__ W1,
    float* __restrict__ s1, int nRows)
{
    const int lane = threadIdx.x & 63;
    const int wid  = blockIdx.x * (blockDim.x >> 6) + (threadIdx.x >> 6);
    const int nw   = gridDim.x * (blockDim.x >> 6);

    float w[2][4][8];
#pragma unroll
    for (int i = 0; i < 2; ++i)
#pragma unroll
        for (int c = 0; c < 4; ++c) {
            const int k = 4 * lane + 256 * i + c;
#pragma unroll
            for (int j = 0; j < HID; ++j)
                w[i][c][j] = (k < IN_DIM) ? W1[k * HID + j] : 0.0f;
        }

    for (int row = wid; row < nRows; row += nw) {
        const float* xr = x + (size_t)row * IN_DIM;
        float acc[8] = {0.f, 0.f, 0.f, 0.f, 0.f, 0.f, 0.f, 0.f};
#pragma unroll
        for (int i = 0; i < 2; ++i) {
            const int k = 4 * lane + 256 * i;
            float4 v = make_float4(0.f, 0.f, 0.f, 0.f);
            if (k + 3 < IN_DIM) v = *(const float4*)(xr + k);
#pragma unroll
            for (int j = 0; j < HID; ++j)
                acc[j] += v.x * w[i][0][j] + v.y * w[i][1][j]
                        + v.z * w[i][2][j] + v.w * w[i][3][j];
        }
#pragma unroll
        for (int m = 32; m >= 1; m >>= 1)
#pragma unroll
            for (int j = 0; j < HID; ++j)
                acc[j] += __shfl_xor(acc[j], m, 64);
        if (lane == 0) {
            float4* o = (float4*)(s1 + (size_t)row * HID);
            o[0] = make_float4(acc[0], acc[1], acc[2], acc[3]);
            o[1] = make_float4(acc[4], acc[5], acc[6], acc[7]);
        }
    }
}

// ---------------------------------------------------------------------------
// Kernel B1: per-block bucket histogram -> counts[block][b]  (no global atomics)
// ---------------------------------------------------------------------------
__global__ __launch_bounds__(1024) void k_count(
    const int* __restrict__ dst, int nE, int chunk,
    unsigned* __restrict__ counts)
{
    __shared__ unsigned lh[NB];
    for (int i = threadIdx.x; i < NB; i += 1024) lh[i] = 0;
    __syncthreads();
    const int beg = blockIdx.x * chunk;
    const int end = min(nE, beg + chunk);
    for (int e = beg + threadIdx.x; e < end; e += 1024)
        atomicAdd(&lh[((unsigned)dst[e]) >> BSHIFT], 1u);
    __syncthreads();
    for (int i = threadIdx.x; i < NB; i += 1024)
        counts[(size_t)blockIdx.x * NB + i] = lh[i];
}

// ---------------------------------------------------------------------------
// Kernel B2: column-wise exclusive prefix over counts (in place) + bucket
// starts via LDS scan. One block, 1024 threads (thread = bucket).
// ---------------------------------------------------------------------------
__global__ __launch_bounds__(1024) void k_scanM(
    unsigned* __restrict__ counts, unsigned* __restrict__ starts)
{
    __shared__ unsigned sums[NB];
    const int b = threadIdx.x;
    unsigned run = 0;
    for (int p = 0; p < PBLK; ++p) {
        const unsigned c = counts[(size_t)p * NB + b];
        counts[(size_t)p * NB + b] = run;   // per-block offset within bucket
        run += c;
    }
    const unsigned total = run;
    sums[b] = run;
    __syncthreads();
    for (int off = 1; off < NB; off <<= 1) {
        const unsigned u = (b >= off) ? sums[b - off] : 0u;
        __syncthreads();
        sums[b] += u;
        __syncthreads();
    }
    starts[b] = sums[b] - total;       // exclusive
    if (b == NB - 1) starts[NB] = sums[b];
}

// ---------------------------------------------------------------------------
// Kernel B3: counting-sort edges into buckets; pack (src<<8)|local_dst.
// Zero global atomics: base = starts[b] + counts[block][b].
// ---------------------------------------------------------------------------
__global__ __launch_bounds__(1024) void k_binwrite(
    const int* __restrict__ ei, int nE, int chunk,
    const unsigned* __restrict__ counts, const unsigned* __restrict__ starts,
    unsigned* __restrict__ binned)
{
    __shared__ unsigned lh[NB];
    __shared__ unsigned lbase[NB];
    for (int i = threadIdx.x; i < NB; i += 1024) {
        lh[i] = 0;
        lbase[i] = starts[i] + counts[(size_t)blockIdx.x * NB + i];
    }
    __syncthreads();
    const int beg = blockIdx.x * chunk;
    const int end = min(nE, beg + chunk);
    for (int e = beg + threadIdx.x; e < end; e += 1024) {
        const unsigned d = (unsigned)ei[nE + e];
        const unsigned s = (unsigned)ei[e];
        const unsigned b = d >> BSHIFT;
        const unsigned r = atomicAdd(&lh[b], 1u);
        binned[lbase[b] + r] = (s << 8) | (d & 255u);
    }
}

// ---------------------------------------------------------------------------
// Kernel C: per-bucket gather of layer-1 + fused relu(+b1) @ W2 -> s2 (pad 4)
// acc stride 9 (odd): ds_atomic bank = (9l+j)%32 -> uniform over 32 banks.
// ---------------------------------------------------------------------------
__global__ __launch_bounds__(1024) void k_gather1(
    const unsigned* __restrict__ binned, const unsigned* __restrict__ starts,
    const float* __restrict__ s1, const float* __restrict__ b1,
    const float* __restrict__ W2, float* __restrict__ s2)
{
    __shared__ float acc[256 * S1W];    // 9 KB
    const int t = threadIdx.x;
    for (int i = t; i < 256 * S1W; i += 1024) acc[i] = 0.f;
    __syncthreads();
    const unsigned beg = starts[blockIdx.x];
    const unsigned end = starts[blockIdx.x + 1];

    unsigned i = beg + t;
    for (; i + 3072 < end; i += 4096) {
        const unsigned p0 = binned[i];
        const unsigned p1 = binned[i + 1024];
        const unsigned p2 = binned[i + 2048];
        const unsigned p3 = binned[i + 3072];
        const float4* r0 = (const float4*)(s1 + (size_t)(p0 >> 8) * HID);
        const float4* r1 = (const float4*)(s1 + (size_t)(p1 >> 8) * HID);
        const float4* r2 = (const float4*)(s1 + (size_t)(p2 >> 8) * HID);
        const float4* r3 = (const float4*)(s1 + (size_t)(p3 >> 8) * HID);
        const float4 a0 = r0[0], b0 = r0[1];
        const float4 a1 = r1[0], b1v = r1[1];
        const float4 a2 = r2[0], b2v = r2[1];
        const float4 a3 = r3[0], b3v = r3[1];
        float* q0 = acc + (p0 & 255u) * S1W;
        float* q1 = acc + (p1 & 255u) * S1W;
        float* q2 = acc + (p2 & 255u) * S1W;
        float* q3 = acc + (p3 & 255u) * S1W;
        atomicAdd(q0 + 0, a0.x); atomicAdd(q0 + 1, a0.y);
        atomicAdd(q0 + 2, a0.z); atomicAdd(q0 + 3, a0.w);
        atomicAdd(q0 + 4, b0.x); atomicAdd(q0 + 5, b0.y);
        atomicAdd(q0 + 6, b0.z); atomicAdd(q0 + 7, b0.w);
        atomicAdd(q1 + 0, a1.x); atomicAdd(q1 + 1, a1.y);
        atomicAdd(q1 + 2, a1.z); atomicAdd(q1 + 3, a1.w);
        atomicAdd(q1 + 4, b1v.x); atomicAdd(q1 + 5, b1v.y);
        atomicAdd(q1 + 6, b1v.z); atomicAdd(q1 + 7, b1v.w);
        atomicAdd(q2 + 0, a2.x); atomicAdd(q2 + 1, a2.y);
        atomicAdd(q2 + 2, a2.z); atomicAdd(q2 + 3, a2.w);
        atomicAdd(q2 + 4, b2v.x); atomicAdd(q2 + 5, b2v.y);
        atomicAdd(q2 + 6, b2v.z); atomicAdd(q2 + 7, b2v.w);
        atomicAdd(q3 + 0, a3.x); atomicAdd(q3 + 1, a3.y);
        atomicAdd(q3 + 2, a3.z); atomicAdd(q3 + 3, a3.w);
        atomicAdd(q3 + 4, b3v.x); atomicAdd(q3 + 5, b3v.y);
        atomicAdd(q3 + 6, b3v.z); atomicAdd(q3 + 7, b3v.w);
    }
    for (; i < end; i += 1024) {
        const unsigned p = binned[i];
        const float4* sp = (const float4*)(s1 + (size_t)(p >> 8) * HID);
        const float4 a = sp[0], b = sp[1];
        float* q = acc + (p & 255u) * S1W;
        atomicAdd(q + 0, a.x); atomicAdd(q + 1, a.y);
        atomicAdd(q + 2, a.z); atomicAdd(q + 3, a.w);
        atomicAdd(q + 4, b.x); atomicAdd(q + 5, b.y);
        atomicAdd(q + 6, b.z); atomicAdd(q + 7, b.w);
    }
    __syncthreads();
    if (t < 256) {
        float h[HID];
#pragma unroll
        for (int j = 0; j < HID; ++j)
            h[j] = fmaxf(acc[t * S1W + j] + b1[j], 0.f);
        float o0 = 0.f, o1 = 0.f, o2 = 0.f;
#pragma unroll
        for (int k = 0; k < HID; ++k) {
            o0 += h[k] * W2[k * ODIM + 0];
            o1 += h[k] * W2[k * ODIM + 1];
            o2 += h[k] * W2[k * ODIM + 2];
        }
        const size_t node = ((size_t)blockIdx.x << BSHIFT) + t;
        *(float4*)(s2 + node * 4) = make_float4(o0, o1, o2, 0.f);
    }
}

// ---------------------------------------------------------------------------
// Kernel D: per-bucket gather of layer-2 -> out = acc + b2   (acc stride 5)
// ---------------------------------------------------------------------------
__global__ __launch_bounds__(1024) void k_gather2(
    const unsigned* __restrict__ binned, const unsigned* __restrict__ starts,
    const float* __restrict__ s2, const float* __restrict__ b2,
    float* __restrict__ out)
{
    __shared__ float acc[256 * S2W];    // 5 KB
    const int t = threadIdx.x;
    for (int i = t; i < 256 * S2W; i += 1024) acc[i] = 0.f;
    __syncthreads();
    const unsigned beg = starts[blockIdx.x];
    const unsigned end = starts[blockIdx.x + 1];

    unsigned i = beg + t;
    for (; i + 3072 < end; i += 4096) {
        const unsigned p0 = binned[i];
        const unsigned p1 = binned[i + 1024];
        const unsigned p2 = binned[i + 2048];
        const unsigned p3 = binned[i + 3072];
        const float4 v0 = *(const float4*)(s2 + (size_t)(p0 >> 8) * 4);
        const float4 v1 = *(const float4*)(s2 + (size_t)(p1 >> 8) * 4);
        const float4 v2 = *(const float4*)(s2 + (size_t)(p2 >> 8) * 4);
        const float4 v3 = *(const float4*)(s2 + (size_t)(p3 >> 8) * 4);
        float* q0 = acc + (p0 & 255u) * S2W;
        float* q1 = acc + (p1 & 255u) * S2W;
        float* q2 = acc + (p2 & 255u) * S2W;
        float* q3 = acc + (p3 & 255u) * S2W;
        atomicAdd(q0 + 0, v0.x); atomicAdd(q0 + 1, v0.y); atomicAdd(q0 + 2, v0.z);
        atomicAdd(q1 + 0, v1.x); atomicAdd(q1 + 1, v1.y); atomicAdd(q1 + 2, v1.z);
        atomicAdd(q2 + 0, v2.x); atomicAdd(q2 + 1, v2.y); atomicAdd(q2 + 2, v2.z);
        atomicAdd(q3 + 0, v3.x); atomicAdd(q3 + 1, v3.y); atomicAdd(q3 + 2, v3.z);
    }
    for (; i < end; i += 1024) {
        const unsigned p = binned[i];
        const float4 v = *(const float4*)(s2 + (size_t)(p >> 8) * 4);
        float* q = acc + (p & 255u) * S2W;
        atomicAdd(q + 0, v.x); atomicAdd(q + 1, v.y); atomicAdd(q + 2, v.z);
    }
    __syncthreads();
    if (t < 256 * ODIM) {
        const int n = t / ODIM, j = t - n * ODIM;
        const size_t base = ((size_t)blockIdx.x << BSHIFT) * ODIM;
        out[base + t] = acc[n * S2W + j] + b2[j];
    }
}

// ---------------------------------------------------------------------------
extern "C" void kernel_launch(void* const* d_in, const int* in_sizes, int n_in,
                              void* d_out, int out_size, void* d_ws, size_t ws_size,
                              hipStream_t stream)
{
    const float* x  = (const float*)d_in[0];
    const int*   ei = (const int*)d_in[1];   // [2, E] int32, row0=src row1=dst
    const float* W1 = (const float*)d_in[2];
    const float* b1 = (const float*)d_in[3];
    const float* W2 = (const float*)d_in[4];
    const float* b2 = (const float*)d_in[5];
    float* out = (float*)d_out;

    const int nE = in_sizes[1] / 2;           // 8388608
    const int nN = in_sizes[0] / IN_DIM;      // 262144

    // workspace layout (~46.6 MB)
    unsigned* binned = (unsigned*)d_ws;                       // nE u32 = 33.5 MB
    float*    s1     = (float*)(binned + nE);                 // nN*8 f32 = 8 MB
    float*    s2     = s1 + (size_t)nN * HID;                 // nN*4 f32 = 4 MB
    unsigned* counts = (unsigned*)(s2 + (size_t)nN * 4);      // PBLK*NB u32 = 1 MB
    unsigned* starts = counts + (size_t)PBLK * NB;            // NB+1

    const int chunk = (nE + PBLK - 1) / PBLK;

    k_support1<<<4096, 256,  0, stream>>>(x, W1, s1, nN);
    k_count   <<<PBLK, 1024, 0, stream>>>(ei + nE, nE, chunk, counts);
    k_scanM   <<<1,    1024, 0, stream>>>(counts, starts);
    k_binwrite<<<PBLK, 1024, 0, stream>>>(ei, nE, chunk, counts, starts, binned);
    k_gather1 <<<NB,   1024, 0, stream>>>(binned, starts, s1, b1, W2, s2);
    k_gather2 <<<NB,   1024, 0, stream>>>(binned, starts, s2, b2, out);
}